// Round 11
// baseline (191.115 us; speedup 1.0000x reference)
//
#include <hip/hip_runtime.h>
#include <math.h>

// Canny, round 10 (resubmit after infra failure): r5 body (simplest,
// lowest-VGPR) with SH=4 for maximum thread-level parallelism: 10240 waves /
// 2560 blocks -> ~8 waves/SIMD resident. Theory: duration pinned at ~45us
// across r5..r8 while per-wave work fell -> exposed memory/shfl latency
// needs more waves, not better per-wave scheduling.
// B=16, C=3, H=W=512 fixed. No LDS, no barriers.

typedef float v2f __attribute__((ext_vector_type(2)));

#define HDIM 512
#define WDIM 512
#define SH   4
#define NSTR (HDIM / SH)   // 128 strips
#define NGRP 5             // 5 x 112 = 560 >= 512
#define GW   112

__device__ __forceinline__ float shfl1(float v, int src) {
    return __shfl(v, src, 64);
}

template<bool RE, bool CE>
__device__ __forceinline__ void run(
    const float* __restrict__ xb0, float t, float* __restrict__ out,
    int b, int R0, int c0, int lane)
{
    const bool colok = !CE || ((unsigned)c0 < (unsigned)WDIM);

    const float w0 = 0.05448868454964294f;   // gauss5(sigma=1)/sum
    const float w1 = 0.24420134200323332f;
    const float w2 = 0.4026199468942475f;
    const float T1c = 0.41421356237309503f;  // tan(pi/8)
    const float T3c = 2.414213562373095f;    // tan(3pi/8)

    auto ld2 = [&](int c, int ri) -> v2f {
        if ((CE && !colok) || (RE && (unsigned)ri >= (unsigned)HDIM)) {
            v2f z = {0.f, 0.f};
            return z;
        }
        return *(const v2f*)(xb0 + c * (HDIM * WDIM) + ri * WDIM + c0);
    };
    // horizontal 5-tap blur on a column pair (packed)
    auto hb2 = [&](v2f v) -> v2f {
        v2f L, R;
        L.x = shfl1(v.x, lane - 1); L.y = shfl1(v.y, lane - 1);
        R.x = shfl1(v.x, lane + 1); R.y = shfl1(v.y, lane + 1);
        v2f p = {L.y, v.x};
        v2f q = {v.y, R.x};
        return w0 * (L + R) + w1 * (p + q) + w2 * v;
    };
    auto dirof = [&](float gx, float gy) -> int {
        const float gys = (gy == 0.f) ? 1e-9f : gy;
        const float sg  = (gys > 0.f) ? 1.f : -1.f;
        const float gxs = gx * sg;            // a>=c  <=>  gxs >= c*|gys|
        const float gya = fabsf(gys);
        const float a3 = T3c * gya, a1 = T1c * gya;
        return (gxs >= a3 || gxs < -a3) ? 2
             : (gxs >= a1) ? 1
             : (gxs >= -a1) ? 0 : 3;
    };

    // rolling state
    v2f xa[3], xbw[3], xcw[3], xdw[3];   // x rows m-1..m+2
    v2f blm[3], bl0[3];                  // blurred rows m-1, m
    v2f xnext[3];                        // prefetched x row
    v2f mg0 = {0.f, 0.f}, mg1 = {0.f, 0.f}, mg2 = {0.f, 0.f};
    int d1x = 0, d1y = 0, d2x = 0, d2y = 0;

    // ---- prologue: bl rows R0-2, R0-1; x window R0-2..R0+1; prefetch R0+2
    #pragma unroll
    for (int c = 0; c < 3; ++c) {
        v2f t0 = ld2(c, R0 - 4), t1 = ld2(c, R0 - 3), t2 = ld2(c, R0 - 2);
        v2f t3 = ld2(c, R0 - 1), t4 = ld2(c, R0),     t5 = ld2(c, R0 + 1);
        v2f vA = w0 * (t0 + t4) + w1 * (t1 + t3) + w2 * t2;  // vb row R0-2
        v2f vB = w0 * (t1 + t5) + w1 * (t2 + t4) + w2 * t3;  // vb row R0-1
        blm[c] = hb2(vA);
        bl0[c] = hb2(vB);
        xa[c] = t2; xbw[c] = t3; xcw[c] = t4; xdw[c] = t5;
        xnext[c] = ld2(c, R0 + 2);
    }

    auto nms_store = [&](int row) {
        float m0l = shfl1(mg0.y, lane - 1), m0r = shfl1(mg0.x, lane + 1);
        float m1l = shfl1(mg1.y, lane - 1), m1r = shfl1(mg1.x, lane + 1);
        float m2l = shfl1(mg2.y, lane - 1), m2r = shfl1(mg2.x, lane + 1);
        // element .x (col c0): left neighbor = m*l, right = own .y
        float n1x = (d1x == 0) ? mg0.x : (d1x == 1) ? m0l
                  : (d1x == 2) ? m1l   : mg0.y;
        float n2x = (d1x == 0) ? mg2.x : (d1x == 1) ? mg2.y
                  : (d1x == 2) ? mg1.y : m2l;
        // element .y (col c0+1): left = own .x, right = m*r
        float n1y = (d1y == 0) ? mg0.y : (d1y == 1) ? mg0.x
                  : (d1y == 2) ? mg1.x : m0r;
        float n2y = (d1y == 0) ? mg2.y : (d1y == 1) ? m2r
                  : (d1y == 2) ? m1r   : mg2.x;
        float sx = (mg1.x >= n1x && mg1.x >= n2x) ? mg1.x : 0.f;
        float sy = (mg1.y >= n1y && mg1.y >= n2y) ? mg1.y : 0.f;
        float vx = (sx >= t) ? sx : 1e-9f;
        float vy = (sy >= t) ? sy : 1e-9f;
        v2f o;
        o.x = __builtin_amdgcn_rcpf(1.f + __expf(-vx));
        o.y = __builtin_amdgcn_rcpf(1.f + __expf(-vy));
        bool doit = (lane >= 4 && lane < 60);
        if (CE) doit = doit && colok;
        if (doit)
            *(v2f*)&out[((size_t)b * HDIM + row) * WDIM + c0] = o;
    };

    // ---- main loop: step m computes mag[m], outputs row m-2 ----
    for (int m = R0 - 1; m <= R0 + SH; ++m) {
        v2f xn[3];
        #pragma unroll
        for (int c = 0; c < 3; ++c) xn[c] = xnext[c];
        if (m < R0 + SH) {                 // prefetch row m+4 for next iter
            #pragma unroll
            for (int c = 0; c < 3; ++c) xnext[c] = ld2(c, m + 4);
        }

        if (m >= R0 + 2) nms_store(m - 2);

        v2f best = {-1.f, -1.f}, bgx = {0.f, 0.f}, bgy = {0.f, 0.f};
        #pragma unroll
        for (int c = 0; c < 3; ++c) {
            v2f vb = w0 * (xa[c] + xn[c]) + w1 * (xbw[c] + xdw[c])
                   + w2 * xcw[c];                   // vb row m+1
            v2f blp = hb2(vb);                      // bl row m+1
            v2f bm = blm[c], bp = blp;
            if (RE) {                               // row edge-replicate
                if (m == 0)        bm = bl0[c];
                if (m == HDIM - 1) bp = bl0[c];
            }
            v2f tt = bm + 2.f * bl0[c] + bp;        // column sums
            v2f uu = bp - bm;
            float tly = shfl1(tt.y, lane - 1), trx = shfl1(tt.x, lane + 1);
            float uly = shfl1(uu.y, lane - 1), urx = shfl1(uu.x, lane + 1);
            if (CE) {                               // col edge-replicate
                if (c0 == 0)            { tly = tt.x; uly = uu.x; }
                if (c0 + 1 == WDIM - 1) { trx = tt.y; urx = uu.y; }
            }
            v2f gA = {tt.y, trx}, gB = {tly, tt.x};
            v2f gxv = 0.125f * (gA - gB);
            v2f hA = {uly, uu.x}, hB = {uu.y, urx};
            v2f gyv = 0.125f * (hA + 2.f * uu + hB);
            v2f m2v = gxv * gxv + gyv * gyv;
            if (m2v.x > best.x) { best.x = m2v.x; bgx.x = gxv.x; bgy.x = gyv.x; }
            if (m2v.y > best.y) { best.y = m2v.y; bgx.y = gxv.y; bgy.y = gyv.y; }
            blm[c] = bl0[c]; bl0[c] = blp;
            xa[c] = xbw[c]; xbw[c] = xcw[c]; xcw[c] = xdw[c]; xdw[c] = xn[c];
        }
        v2f mag2;
        mag2.x = __builtin_amdgcn_sqrtf(best.x + 1e-9f);
        mag2.y = __builtin_amdgcn_sqrtf(best.y + 1e-9f);
        if (RE && (unsigned)m >= (unsigned)HDIM) { mag2.x = 0.f; mag2.y = 0.f; }
        if (CE && !colok)                        { mag2.x = 0.f; mag2.y = 0.f; }
        const int dnx = dirof(bgx.x, bgy.x);
        const int dny = dirof(bgx.y, bgy.y);
        mg0 = mg1; mg1 = mg2; mg2 = mag2;
        d1x = d2x; d1y = d2y; d2x = dnx; d2y = dny;
    }
    nms_store(R0 + SH - 1);   // last output row
}

__global__ __launch_bounds__(256, 8) void canny_tlp(
    const float* __restrict__ x, const int* __restrict__ lt,
    float* __restrict__ out)
{
    const int lane = threadIdx.x & 63;
    const int wid  = blockIdx.x * 4 + (threadIdx.x >> 6);
    const int b    = wid / (NGRP * NSTR);
    const int rem  = wid - b * (NGRP * NSTR);
    const int g    = rem >> 7;        // NSTR = 128
    const int s    = rem & (NSTR - 1);
    const int R0   = s * SH;
    const int c0   = g * GW + 2 * lane - 8;   // pair base col (even)
    const float t  = (float)lt[0];
    const float* xb0 = x + (size_t)(b * 3) * (HDIM * WDIM);

    const bool re = (s == 0) || (s == NSTR - 1);
    const bool ce = (g == 0) || (g == NGRP - 1);
    if (!re && !ce)      run<false, false>(xb0, t, out, b, R0, c0, lane);
    else if (!re)        run<false, true >(xb0, t, out, b, R0, c0, lane);
    else if (!ce)        run<true,  false>(xb0, t, out, b, R0, c0, lane);
    else                 run<true,  true >(xb0, t, out, b, R0, c0, lane);
}

extern "C" void kernel_launch(void* const* d_in, const int* in_sizes, int n_in,
                              void* d_out, int out_size, void* d_ws, size_t ws_size,
                              hipStream_t stream) {
    const float* x  = (const float*)d_in[0];
    const int*   lt = (const int*)d_in[1];
    float* out = (float*)d_out;
    // 16 b x 5 groups x 128 strips = 10240 waves = 2560 blocks
    const int nblocks = (16 * NGRP * NSTR) / 4;
    canny_tlp<<<nblocks, dim3(256), 0, stream>>>(x, lt, out);
}

// Round 12
// 113.818 us; speedup vs baseline: 1.6791x; 1.6791x over previous
//
#include <hip/hip_runtime.h>
#include <math.h>

// Canny, round 12: r5 body, SH=4 (10240 waves), VALID occupancy experiment:
//  - plain __launch_bounds__(256): NO VGPR squeeze (r11's (256,8) forced
//    VGPR 48->32 => scratch spills => WRITE 16->165MB, FETCH thrash, 123us)
//  - XCD-aware swizzle: each XCD gets a contiguous band of strips so halo
//    re-reads between adjacent strips hit that XCD's 4MB L2.
// B=16, C=3, H=W=512 fixed. No LDS, no barriers.

typedef float v2f __attribute__((ext_vector_type(2)));

#define HDIM 512
#define WDIM 512
#define SH   4
#define NSTR (HDIM / SH)   // 128 strips
#define NGRP 5             // 5 x 112 = 560 >= 512
#define GW   112
#define NBLK ((16 * NGRP * NSTR) / 4)   // 2560 blocks

__device__ __forceinline__ float shfl1(float v, int src) {
    return __shfl(v, src, 64);
}

template<bool RE, bool CE>
__device__ __forceinline__ void run(
    const float* __restrict__ xb0, float t, float* __restrict__ out,
    int b, int R0, int c0, int lane)
{
    const bool colok = !CE || ((unsigned)c0 < (unsigned)WDIM);

    const float w0 = 0.05448868454964294f;   // gauss5(sigma=1)/sum
    const float w1 = 0.24420134200323332f;
    const float w2 = 0.4026199468942475f;
    const float T1c = 0.41421356237309503f;  // tan(pi/8)
    const float T3c = 2.414213562373095f;    // tan(3pi/8)

    auto ld2 = [&](int c, int ri) -> v2f {
        if ((CE && !colok) || (RE && (unsigned)ri >= (unsigned)HDIM)) {
            v2f z = {0.f, 0.f};
            return z;
        }
        return *(const v2f*)(xb0 + c * (HDIM * WDIM) + ri * WDIM + c0);
    };
    // horizontal 5-tap blur on a column pair (packed)
    auto hb2 = [&](v2f v) -> v2f {
        v2f L, R;
        L.x = shfl1(v.x, lane - 1); L.y = shfl1(v.y, lane - 1);
        R.x = shfl1(v.x, lane + 1); R.y = shfl1(v.y, lane + 1);
        v2f p = {L.y, v.x};
        v2f q = {v.y, R.x};
        return w0 * (L + R) + w1 * (p + q) + w2 * v;
    };
    auto dirof = [&](float gx, float gy) -> int {
        const float gys = (gy == 0.f) ? 1e-9f : gy;
        const float sg  = (gys > 0.f) ? 1.f : -1.f;
        const float gxs = gx * sg;            // a>=c  <=>  gxs >= c*|gys|
        const float gya = fabsf(gys);
        const float a3 = T3c * gya, a1 = T1c * gya;
        return (gxs >= a3 || gxs < -a3) ? 2
             : (gxs >= a1) ? 1
             : (gxs >= -a1) ? 0 : 3;
    };

    // rolling state
    v2f xa[3], xbw[3], xcw[3], xdw[3];   // x rows m-1..m+2
    v2f blm[3], bl0[3];                  // blurred rows m-1, m
    v2f xnext[3];                        // prefetched x row
    v2f mg0 = {0.f, 0.f}, mg1 = {0.f, 0.f}, mg2 = {0.f, 0.f};
    int d1x = 0, d1y = 0, d2x = 0, d2y = 0;

    // ---- prologue: bl rows R0-2, R0-1; x window R0-2..R0+1; prefetch R0+2
    #pragma unroll
    for (int c = 0; c < 3; ++c) {
        v2f t0 = ld2(c, R0 - 4), t1 = ld2(c, R0 - 3), t2 = ld2(c, R0 - 2);
        v2f t3 = ld2(c, R0 - 1), t4 = ld2(c, R0),     t5 = ld2(c, R0 + 1);
        v2f vA = w0 * (t0 + t4) + w1 * (t1 + t3) + w2 * t2;  // vb row R0-2
        v2f vB = w0 * (t1 + t5) + w1 * (t2 + t4) + w2 * t3;  // vb row R0-1
        blm[c] = hb2(vA);
        bl0[c] = hb2(vB);
        xa[c] = t2; xbw[c] = t3; xcw[c] = t4; xdw[c] = t5;
        xnext[c] = ld2(c, R0 + 2);
    }

    auto nms_store = [&](int row) {
        float m0l = shfl1(mg0.y, lane - 1), m0r = shfl1(mg0.x, lane + 1);
        float m1l = shfl1(mg1.y, lane - 1), m1r = shfl1(mg1.x, lane + 1);
        float m2l = shfl1(mg2.y, lane - 1), m2r = shfl1(mg2.x, lane + 1);
        // element .x (col c0): left neighbor = m*l, right = own .y
        float n1x = (d1x == 0) ? mg0.x : (d1x == 1) ? m0l
                  : (d1x == 2) ? m1l   : mg0.y;
        float n2x = (d1x == 0) ? mg2.x : (d1x == 1) ? mg2.y
                  : (d1x == 2) ? mg1.y : m2l;
        // element .y (col c0+1): left = own .x, right = m*r
        float n1y = (d1y == 0) ? mg0.y : (d1y == 1) ? mg0.x
                  : (d1y == 2) ? mg1.x : m0r;
        float n2y = (d1y == 0) ? mg2.y : (d1y == 1) ? m2r
                  : (d1y == 2) ? m1r   : mg2.x;
        float sx = (mg1.x >= n1x && mg1.x >= n2x) ? mg1.x : 0.f;
        float sy = (mg1.y >= n1y && mg1.y >= n2y) ? mg1.y : 0.f;
        float vx = (sx >= t) ? sx : 1e-9f;
        float vy = (sy >= t) ? sy : 1e-9f;
        v2f o;
        o.x = __builtin_amdgcn_rcpf(1.f + __expf(-vx));
        o.y = __builtin_amdgcn_rcpf(1.f + __expf(-vy));
        bool doit = (lane >= 4 && lane < 60);
        if (CE) doit = doit && colok;
        if (doit)
            *(v2f*)&out[((size_t)b * HDIM + row) * WDIM + c0] = o;
    };

    // ---- main loop: step m computes mag[m], outputs row m-2 ----
    for (int m = R0 - 1; m <= R0 + SH; ++m) {
        v2f xn[3];
        #pragma unroll
        for (int c = 0; c < 3; ++c) xn[c] = xnext[c];
        if (m < R0 + SH) {                 // prefetch row m+4 for next iter
            #pragma unroll
            for (int c = 0; c < 3; ++c) xnext[c] = ld2(c, m + 4);
        }

        if (m >= R0 + 2) nms_store(m - 2);

        v2f best = {-1.f, -1.f}, bgx = {0.f, 0.f}, bgy = {0.f, 0.f};
        #pragma unroll
        for (int c = 0; c < 3; ++c) {
            v2f vb = w0 * (xa[c] + xn[c]) + w1 * (xbw[c] + xdw[c])
                   + w2 * xcw[c];                   // vb row m+1
            v2f blp = hb2(vb);                      // bl row m+1
            v2f bm = blm[c], bp = blp;
            if (RE) {                               // row edge-replicate
                if (m == 0)        bm = bl0[c];
                if (m == HDIM - 1) bp = bl0[c];
            }
            v2f tt = bm + 2.f * bl0[c] + bp;        // column sums
            v2f uu = bp - bm;
            float tly = shfl1(tt.y, lane - 1), trx = shfl1(tt.x, lane + 1);
            float uly = shfl1(uu.y, lane - 1), urx = shfl1(uu.x, lane + 1);
            if (CE) {                               // col edge-replicate
                if (c0 == 0)            { tly = tt.x; uly = uu.x; }
                if (c0 + 1 == WDIM - 1) { trx = tt.y; urx = uu.y; }
            }
            v2f gA = {tt.y, trx}, gB = {tly, tt.x};
            v2f gxv = 0.125f * (gA - gB);
            v2f hA = {uly, uu.x}, hB = {uu.y, urx};
            v2f gyv = 0.125f * (hA + 2.f * uu + hB);
            v2f m2v = gxv * gxv + gyv * gyv;
            if (m2v.x > best.x) { best.x = m2v.x; bgx.x = gxv.x; bgy.x = gyv.x; }
            if (m2v.y > best.y) { best.y = m2v.y; bgx.y = gxv.y; bgy.y = gyv.y; }
            blm[c] = bl0[c]; bl0[c] = blp;
            xa[c] = xbw[c]; xbw[c] = xcw[c]; xcw[c] = xdw[c]; xdw[c] = xn[c];
        }
        v2f mag2;
        mag2.x = __builtin_amdgcn_sqrtf(best.x + 1e-9f);
        mag2.y = __builtin_amdgcn_sqrtf(best.y + 1e-9f);
        if (RE && (unsigned)m >= (unsigned)HDIM) { mag2.x = 0.f; mag2.y = 0.f; }
        if (CE && !colok)                        { mag2.x = 0.f; mag2.y = 0.f; }
        const int dnx = dirof(bgx.x, bgy.x);
        const int dny = dirof(bgx.y, bgy.y);
        mg0 = mg1; mg1 = mg2; mg2 = mag2;
        d1x = d2x; d1y = d2y; d2x = dnx; d2y = dny;
    }
    nms_store(R0 + SH - 1);   // last output row
}

__global__ __launch_bounds__(256) void canny_occ(
    const float* __restrict__ x, const int* __restrict__ lt,
    float* __restrict__ out)
{
    const int lane = threadIdx.x & 63;
    // XCD swizzle: presumed xcd = blockIdx.x % 8 (round-robin). Give XCD k
    // the contiguous work band [k*320, (k+1)*320) so vertically-adjacent
    // strips (shared halo rows) reuse the same XCD's L2. Pure perf
    // heuristic: any mapping is a bijection, so correctness is unaffected.
    const int X  = blockIdx.x;
    const int Xw = (X & 7) * (NBLK / 8) + (X >> 3);
    const int wid  = Xw * 4 + (threadIdx.x >> 6);
    const int b    = wid / (NGRP * NSTR);
    const int rem  = wid - b * (NGRP * NSTR);
    const int g    = rem >> 7;        // NSTR = 128
    const int s    = rem & (NSTR - 1);
    const int R0   = s * SH;
    const int c0   = g * GW + 2 * lane - 8;   // pair base col (even)
    const float t  = (float)lt[0];
    const float* xb0 = x + (size_t)(b * 3) * (HDIM * WDIM);

    const bool re = (s == 0) || (s == NSTR - 1);
    const bool ce = (g == 0) || (g == NGRP - 1);
    if (!re && !ce)      run<false, false>(xb0, t, out, b, R0, c0, lane);
    else if (!re)        run<false, true >(xb0, t, out, b, R0, c0, lane);
    else if (!ce)        run<true,  false>(xb0, t, out, b, R0, c0, lane);
    else                 run<true,  true >(xb0, t, out, b, R0, c0, lane);
}

extern "C" void kernel_launch(void* const* d_in, const int* in_sizes, int n_in,
                              void* d_out, int out_size, void* d_ws, size_t ws_size,
                              hipStream_t stream) {
    const float* x  = (const float*)d_in[0];
    const int*   lt = (const int*)d_in[1];
    float* out = (float*)d_out;
    // 16 b x 5 groups x 128 strips = 10240 waves = 2560 blocks
    canny_occ<<<NBLK, dim3(256), 0, stream>>>(x, lt, out);
}